// Round 10
// baseline (245.647 us; speedup 1.0000x reference)
//
#include <hip/hip_runtime.h>

// Median filter (k=22, REFLECT) + blend, NHWC (2,224,224,3) fp32.
// SHARED-SCAN STRIP kernel: one wave owns 8 consecutive-x pixels. The union
// window (22 rows x 29 cols = 638 elems) lives in 10 regs/lane, laid out
// column-major in slot order (slot = col*22 + row), so one threshold scan
// (10 v_cmp ballots) yields ALL 8 pixel counts via contiguous 22-bit column
// slices + prefix sums (scalar-pipe work). Probing: count at 0.5 -> Newton-
// centered 11-point ladder (spacing 0.004 ~ 2 ranks); per-pixel best (t,C).
// Exact terminal: sign-folded max-peel per pixel (R6-proven, duplicate-
// aware); window membership = contiguous slot-range test (plain C cndmask,
// no inline asm - R9's compile failure removed). Reflect baked into the
// gather -> zero edge divergence.

#define HH 224
#define WW 224
#define CHN 3
#define KK 22
#define PT 10             // pad top/left; bottom/right = 11
#define AREA (KK * KK)    // 484
#define RANK 242          // median = 242nd smallest (1-indexed)
#define PXW 8
#define XGS (WW / PXW)    // 28
#define UC (PXW + KK - 1) // 29 union columns
#define NSLOT (UC * KK)   // 638
#define NREG 10
#define LADK 11
#define LADSP 0.004f

#define INFF  __int_as_float(0x7f800000)
#define NINFF __int_as_float(0xff800000)

__device__ __forceinline__ int reflect224(int g) {
    int a = abs(g);
    return min(a, 2 * (HH - 1) - a);
}

// one shared scan: all 8 pixel counts for threshold t (slices on scalar pipe)
__device__ __forceinline__ void scan_counts(const float v[NREG], float t,
                                            int Cp[PXW]) {
    unsigned long long m[NREG];
#pragma unroll
    for (int r = 0; r < NREG; ++r)
        m[r] = __ballot(v[r] < t);
    int colc[UC];
#pragma unroll
    for (int j = 0; j < UC; ++j) {
        const int s  = KK * j;
        const int w  = s >> 6;
        const int sh = s & 63;
        unsigned long long bits = m[w] >> sh;
        if (sh > 64 - KK) bits |= m[w + 1] << (64 - sh);
        colc[j] = __popcll(bits & 0x3FFFFFull);
    }
    int pref[UC + 1];
    pref[0] = 0;
#pragma unroll
    for (int j = 0; j < UC; ++j) pref[j + 1] = pref[j] + colc[j];
#pragma unroll
    for (int p = 0; p < PXW; ++p)
        Cp[p] = pref[p + KK] - pref[p];
}

__global__ __launch_bounds__(256)
void median_blend_kernel(const float* __restrict__ in,
                         const float* __restrict__ blend,
                         float* __restrict__ out) {
    const int lane = threadIdx.x & 63;
    const int wid  = threadIdx.x >> 6;
    const int wg = blockIdx.x * 4 + wid;        // wave-uniform strip id
    // wg = ((b*CHN + c)*HH + y)*XGS + xg
    const int xg = wg % XGS;
    const int t1 = wg / XGS;
    const int y  = t1 % HH;
    const int t2 = t1 / HH;
    const int c  = t2 % CHN;
    const int b  = t2 / CHN;

    const float f = blend[0];
    const float* img  = in  + (size_t)b * (HH * WW * CHN) + c;
    float*       outp = out + (size_t)b * (HH * WW * CHN) + c;
    const int x0 = xg * PXW;

    // ---- gather union window (column-major slots); reflect for everyone ----
    float v[NREG];
#pragma unroll
    for (int r = 0; r < NREG; ++r) {
        int slot = r * 64 + lane;
        if (slot > NSLOT - 1) slot = NSLOT - 1;   // slots 638/639: dup of 637
        int col = slot / KK;                      // 0..28
        int row = slot - col * KK;                // 0..21
        int gy = reflect224(y - PT + row);
        int gx = reflect224(x0 - PT + col);
        v[r] = img[gy * (WW * CHN) + gx * CHN];
    }
    // (clamped slots contaminate only bits 638/639: no column slice reads
    //  them, and the peel's slot-range test excludes them.)

    // ---- probe 1 at 0.5 + Newton-centered 11-point ladder ----
    float tb[PXW]; int Cb[PXW]; int sc[PXW];
    {
        int C0[PXW];
        scan_counts(v, 0.5f, C0);
        int sum = 0;
#pragma unroll
        for (int p = 0; p < PXW; ++p) {
            tb[p] = 0.5f; Cb[p] = C0[p]; sc[p] = abs(C0[p] - RANK);
            sum += C0[p];
        }
        const float tc = 0.5f + (float)(RANK * PXW - sum) *
                         (1.0f / (float)(AREA * PXW));
#pragma unroll 1
        for (int k = 0; k < LADK; ++k) {
            float t = tc + (float)(k - LADK / 2) * LADSP;
            int Cp[PXW];
            scan_counts(v, t, Cp);
#pragma unroll
            for (int p = 0; p < PXW; ++p) {
                int s = abs(Cp[p] - RANK);
                if (s < sc[p]) { sc[p] = s; Cb[p] = Cp[p]; tb[p] = t; }
            }
        }
    }

    // ---- per-pixel exact sign-folded max-peel + blend/store ----
#pragma unroll 1
    for (int p = 0; p < PXW; ++p) {
        const int d = Cb[p] - RANK;
        const bool top = (d >= 0);
        int e = top ? d + 1 : -d;               // rank within candidate set
        const int sgn = top ? 0 : (int)0x80000000;
        const float t = tb[p];
        const int s0 = KK * p;                  // window = slots [s0, s0+484)

        float w[NREG];
#pragma unroll
        for (int r = 0; r < NREG; ++r) {
            int slotid = r * 64 + lane;
            bool inwin  = (unsigned)(slotid - s0) < (unsigned)AREA;
            bool member = top ? (v[r] < t) : (v[r] >= t);
            float sv = __int_as_float(__float_as_int(v[r]) ^ sgn);
            w[r] = (inwin && member) ? sv : NINFF;
        }

        float med = t;                           // provably overwritten
#pragma unroll 1
        for (int rd = 0; rd < 500; ++rd) {
            float m = w[0];
#pragma unroll
            for (int r = 1; r < NREG; ++r) m = fmaxf(m, w[r]);
#pragma unroll
            for (int off = 32; off > 0; off >>= 1)
                m = fmaxf(m, __shfl_xor(m, off, 64));
            int q = 0;
#pragma unroll
            for (int r = 0; r < NREG; ++r)
                q += __popcll(__ballot(w[r] == m));
            if (e <= q) { med = __int_as_float(__float_as_int(m) ^ sgn); break; }
            e -= q;
#pragma unroll
            for (int r = 0; r < NREG; ++r)
                w[r] = (w[r] == m) ? NINFF : w[r];
        }

        const int x = x0 + p;
        const float xc = img[y * (WW * CHN) + x * CHN];
        if (lane == 0)
            outp[y * (WW * CHN) + x * CHN] = med + f * (xc - med);
    }
}

extern "C" void kernel_launch(void* const* d_in, const int* in_sizes, int n_in,
                              void* d_out, int out_size, void* d_ws, size_t ws_size,
                              hipStream_t stream) {
    const float* in    = (const float*)d_in[0];
    const float* blend = (const float*)d_in[1];
    float* out = (float*)d_out;

    const int nwaves  = 2 * CHN * HH * XGS;   // 37632 strips
    const int nblocks = nwaves / 4;           // 9408
    median_blend_kernel<<<nblocks, 256, 0, stream>>>(in, blend, out);
}

// Round 11
// 164.875 us; speedup vs baseline: 1.4899x; 1.4899x over previous
//
#include <hip/hip_runtime.h>

// Median filter (k=22, REFLECT) + blend, NHWC (2,224,224,3) fp32.
// R6 core (one wave per 8-px strip, pairs in lockstep, warm-started interp
// probes + sign-folded pair peel; exact incl. REFLECT duplicates) with the
// scaffold cost attacked: wg is forced wave-uniform via readfirstlane so all
// strip coords / base pointers live in SGPRs -> interior gathers are
// saddr+voffset loads with ZERO per-load VALU address math, xc becomes a
// scalar load, store addressing goes scalar. Edge-reflect handling hoisted
// to strip level (only 4/28 strips take the per-lane reflect path).

#define HH 224
#define WW 224
#define CHN 3
#define KK 22
#define PT 10            // pad top/left; bottom/right = 11
#define AREA (KK * KK)   // 484
#define RANK 242         // median = 242nd smallest (1-indexed)
#define PXW 8
#define XGS (WW / PXW)   // 28
#define DT 2             // peel when |count-RANK| <= DT

#define INFF  __int_as_float(0x7f800000)
#define NINFF __int_as_float(0xff800000)

__device__ __forceinline__ int reflect224(int g) {
    int a = abs(g);
    return min(a, 2 * (HH - 1) - a);
}

__device__ __forceinline__ int count8(const float v[8], float t) {
    int c = 0;
#pragma unroll
    for (int i = 0; i < 8; ++i)
        c += __popcll(__ballot(v[i] < t));
    return c;
}

__global__ __launch_bounds__(256)
void median_blend_kernel(const float* __restrict__ in,
                         const float* __restrict__ blend,
                         float* __restrict__ out) {
    const int lane = threadIdx.x & 63;
    // Force wave-uniformity into the compiler's divergence analysis: wg and
    // everything derived from it land in SGPRs.
    const int wg = __builtin_amdgcn_readfirstlane(blockIdx.x * 4 + (threadIdx.x >> 6));
    // wg = ((b*CHN + c)*HH + y)*XGS + xg
    const int xg = wg % XGS;
    const int t1 = wg / XGS;
    const int y  = t1 % HH;
    const int t2 = t1 / HH;
    const int c  = t2 % CHN;
    const int b  = t2 / CHN;

    const float f = blend[0];
    const float* img  = in  + (size_t)b * (HH * WW * CHN) + c;   // uniform
    float*       outp = out + (size_t)b * (HH * WW * CHN) + c;   // uniform

    // per-wave lane constants: voff = gy*672 + col*3 (vertical reflect baked in)
    int voff[8], colv[8], gyv[8];
#pragma unroll
    for (int i = 0; i < 8; ++i) {
        int s   = i * 64 + lane;
        int se  = min(s, AREA - 1);
        int row = se / KK;
        int col = se - row * KK;
        int gy  = reflect224(y - PT + row);
        colv[i] = col;
        gyv[i]  = gy * (WW * CHN);
        voff[i] = gyv[i] + col * CHN;
    }

    const int x0 = xg * PXW;
    // strip fully interior iff x0-10 >= 0 and x0+7+11 <= 223
    const bool interior = (x0 >= PT) && (x0 + PXW - 1 + (KK - 1 - PT) <= WW - 1);
    float tprev = 0.5f;

#pragma unroll 1
    for (int j = 0; j < PXW; j += 2) {
        const int xA = x0 + j;
        const int xB = xA + 1;

        float vA[8], vB[8];
        if (interior) {
            const float* baseA = img + (xA - PT) * CHN;   // SGPR base
            const float* baseB = baseA + CHN;
#pragma unroll
            for (int i = 0; i < 8; ++i) vA[i] = baseA[voff[i]];
#pragma unroll
            for (int i = 0; i < 8; ++i) vB[i] = baseB[voff[i]];
        } else {
#pragma unroll
            for (int i = 0; i < 8; ++i) {
                int gxA = reflect224(xA - PT + colv[i]);
                int gxB = reflect224(xB - PT + colv[i]);
                vA[i] = img[gyv[i] + gxA * CHN];
                vB[i] = img[gyv[i] + gxB * CHN];
            }
        }
        vA[7] = (lane < AREA - 448) ? vA[7] : INFF;   // slots >= 484 -> +INF
        vB[7] = (lane < AREA - 448) ? vB[7] : INFF;

        // ---- warm-started interpolation probes, pair in lockstep (R6) ----
        float tA = tprev, tB = tprev;
        int CA = count8(vA, tA);
        int CB = count8(vB, tB);
        float loA = 0.0f, hiA = 1.0f, loB = 0.0f, hiB = 1.0f;
        int cloA = 0, chiA = AREA, cloB = 0, chiB = AREA;
        bool actA = true, actB = true;
#pragma unroll 1
        for (int it = 0; it < 16 && (actA || actB); ++it) {
            if (actA) {
                int d = CA - RANK;
                if (d >= -DT && d <= DT) actA = false;
                else {
                    if (d > 0) { hiA = tA; chiA = CA; }
                    else       { loA = tA; cloA = CA; }
                    float tn = loA + (hiA - loA) * (float)(RANK - cloA) *
                               __builtin_amdgcn_rcpf((float)(chiA - cloA));
                    if (!(tn > loA && tn < hiA)) {
                        tn = 0.5f * (loA + hiA);
                        if (!(tn > loA && tn < hiA)) actA = false;
                    }
                    if (actA) { tA = tn; CA = count8(vA, tA); }
                }
            }
            if (actB) {
                int d = CB - RANK;
                if (d >= -DT && d <= DT) actB = false;
                else {
                    if (d > 0) { hiB = tB; chiB = CB; }
                    else       { loB = tB; cloB = CB; }
                    float tn = loB + (hiB - loB) * (float)(RANK - cloB) *
                               __builtin_amdgcn_rcpf((float)(chiB - cloB));
                    if (!(tn > loB && tn < hiB)) {
                        tn = 0.5f * (loB + hiB);
                        if (!(tn > loB && tn < hiB)) actB = false;
                    }
                    if (actB) { tB = tn; CB = count8(vB, tB); }
                }
            }
        }

        // ---- sign-folded pair peel (R6-proven, exact, duplicate-aware) ----
        const int dA = CA - RANK, dB = CB - RANK;
        const bool topA = (dA >= 0), topB = (dB >= 0);
        int eA = topA ? dA + 1 : -dA;
        int eB = topB ? dB + 1 : -dB;
        const int sgnA = topA ? 0 : (int)0x80000000;
        const int sgnB = topB ? 0 : (int)0x80000000;
#pragma unroll
        for (int i = 0; i < 8; ++i) {
            bool ltA = vA[i] < tA;                 // member iff lt == top
            float sA = __int_as_float(__float_as_int(vA[i]) ^ sgnA);
            vA[i] = (ltA == topA) ? sA : NINFF;
            bool ltB = vB[i] < tB;
            float sB = __int_as_float(__float_as_int(vB[i]) ^ sgnB);
            vB[i] = (ltB == topB) ? sB : NINFF;
        }

        float medA = tA, medB = tB;                // provably overwritten
        bool doneA = false, doneB = false;
#pragma unroll 1
        for (int r = 0; r < 300 && !(doneA && doneB); ++r) {
            float mA = fmaxf(fmaxf(fmaxf(vA[0], vA[1]), fmaxf(vA[2], vA[3])),
                             fmaxf(fmaxf(vA[4], vA[5]), fmaxf(vA[6], vA[7])));
            float mB = fmaxf(fmaxf(fmaxf(vB[0], vB[1]), fmaxf(vB[2], vB[3])),
                             fmaxf(fmaxf(vB[4], vB[5]), fmaxf(vB[6], vB[7])));
#pragma unroll
            for (int off = 32; off > 0; off >>= 1) {
                mA = fmaxf(mA, __shfl_xor(mA, off, 64));
                mB = fmaxf(mB, __shfl_xor(mB, off, 64));
            }
            if (!doneA) {
                int q = 0;
#pragma unroll
                for (int i = 0; i < 8; ++i)
                    q += __popcll(__ballot(vA[i] == mA));
                if (eA <= q) {
                    medA = __int_as_float(__float_as_int(mA) ^ sgnA);
                    doneA = true;
                } else {
                    eA -= q;
#pragma unroll
                    for (int i = 0; i < 8; ++i)
                        vA[i] = (vA[i] == mA) ? NINFF : vA[i];
                }
            }
            if (!doneB) {
                int q = 0;
#pragma unroll
                for (int i = 0; i < 8; ++i)
                    q += __popcll(__ballot(vB[i] == mB));
                if (eB <= q) {
                    medB = __int_as_float(__float_as_int(mB) ^ sgnB);
                    doneB = true;
                } else {
                    eB -= q;
#pragma unroll
                    for (int i = 0; i < 8; ++i)
                        vB[i] = (vB[i] == mB) ? NINFF : vB[i];
                }
            }
        }
        tprev = medB;                              // warm start for next pair

        // ---- blend + store (scalar addresses; lane 0 writes) ----
        const float xcA = img[y * (WW * CHN) + xA * CHN];
        const float xcB = img[y * (WW * CHN) + xB * CHN];
        if (lane == 0) {
            outp[y * (WW * CHN) + xA * CHN] = medA + f * (xcA - medA);
            outp[y * (WW * CHN) + xB * CHN] = medB + f * (xcB - medB);
        }
    }
}

extern "C" void kernel_launch(void* const* d_in, const int* in_sizes, int n_in,
                              void* d_out, int out_size, void* d_ws, size_t ws_size,
                              hipStream_t stream) {
    const float* in    = (const float*)d_in[0];
    const float* blend = (const float*)d_in[1];
    float* out = (float*)d_out;

    const int nwaves  = 2 * CHN * HH * XGS;   // 37632
    const int nblocks = nwaves / 4;           // 9408
    median_blend_kernel<<<nblocks, 256, 0, stream>>>(in, blend, out);
}